// Round 11
// baseline (221.312 us; speedup 1.0000x reference)
//
#include <hip/hip_runtime.h>
#include <stdint.h>

typedef int v4i  __attribute__((ext_vector_type(4)));
typedef int v16i __attribute__((ext_vector_type(16)));

// Problem constants
constexpr int C     = 256;           // channels (in == out)
constexpr int H     = 28, W = 28;
constexpr int HW    = H * W;         // 784
constexpr int NB    = 64;            // batch
constexpr int GP    = NB * HW;       // 50176 flattened pixels
constexpr int CNT   = GP;            // per-channel reduction count
constexpr int TOTAL = NB * C * HW;   // 12,845,056
constexpr int MT    = 128;           // pixels per block (4 m-tiles of 32)
constexpr int NBLK  = GP / MT;       // 392 conv tiles, exact
constexpr int LROWS = 192;           // staged rows: gp0-32 .. gp0+159
constexpr int ZROW  = LROWS * 16;    // zero-row base (v4i index)

// ---------------------------------------------------------------------------
// R16: conv moved to mfma_i32_32x32x32_i8.
// R15 post-mortem: conv is LDS-READ-PIPE-bound — per K-step 4 waves x 28
// ds_read_b128 x 12cyc = 1344 cyc on the CU's single LDS pipe vs 570 cyc
// MFMA wall (all waves redundantly read the same A-frags). 32x32x32 doubles
// MACs per 16B A-read: per K=32 step = 4 A-reads + 2 B-loads + 8 MFMA ->
// LDS 384 cyc/CU < MFMA 640 cyc. Also: finalize re-fused into consumers
// (R15's split-out finalize = +2 boundaries = +10us, zero gain).
//
// Frag mapping (A/B identical; natural extension of verified 16x16x64):
//   operand: lane l holds idx = l&31 (row for A / col for B),
//            k = (l>>5)*16 + e  (16 contiguous i8 = one v4i).
//   C/D (doc-verified, dtype-independent): col = l&31,
//            row = (reg&3) + 8*(reg>>2) + 4*(l>>5), reg in [0,16).
// wbf layout: wbf[((tp*8 + ks)*8 + g)*64 + l], g = co-group of 32.
// +1 -> 0x01, -1 -> 0xFF, zero-pad = 0x00.
// ---------------------------------------------------------------------------

#define SB(f) ((f) < 0.f ? 0xFF : 0x01)

// one channel e: float4 = 4 consecutive pixels; accumulate into per-pixel words
#define XPE(e, pw0, pw1, pw2, pw3, sh) { \
    const float4 v = *(const float4*)(base + (size_t)(e) * HW); \
    pw0 |= SB(v.x) << (sh); pw1 |= SB(v.y) << (sh); \
    pw2 |= SB(v.z) << (sh); pw3 |= SB(v.w) << (sh); }

__global__ void pack_all_kernel(const float* __restrict__ pw1, const float* __restrict__ pw2,
                                const float* __restrict__ x,
                                v4i* __restrict__ wbf1, v4i* __restrict__ wbf2,
                                v4i* __restrict__ xb, double* __restrict__ stats) {
    __shared__ signed char sgn[36864];     // 16 co x 2304 (ci,tap) sign bytes
    const int t = threadIdx.x;
    const int bid = blockIdx.x;
    if (bid < 32) {                        // w-part: (tensor, cg) LDS transpose
        const int cg = bid & 15;           // 16-co block; g = cg>>1, half h = cg&1
        const float* w = (bid >> 4) ? pw2 : pw1;
        v4i* dst       = (bid >> 4) ? wbf2 : wbf1;
        const float4* wg = (const float4*)(w + (size_t)cg * 16 * 2304);
        int* sg4 = (int*)sgn;
        for (int pass = 0; pass < 36; ++pass) {        // 9216 float4 / 256
            const int m4 = pass * 256 + t;
            float4 v = wg[m4];
            int pk = SB(v.x) | (SB(v.y) << 8) | (SB(v.z) << 16) | (SB(v.w) << 24);
            sg4[m4] = pk;
        }
        __syncthreads();
        // thread -> (co_l, lh, ks); lane l = h*16 + co_l + lh*32
        const int co_l = t & 15;
        const int lh   = (t >> 4) & 1;
        const int ks   = t >> 5;                       // 0..7
        const int g    = cg >> 1, h = cg & 1;
        const int lane = h * 16 + co_l + lh * 32;
        const int ci0  = ks * 32 + lh * 16;
        for (int tp = 0; tp < 9; ++tp) {
            int b0 = 0, b1 = 0, b2 = 0, b3 = 0;
#pragma unroll
            for (int e = 0; e < 16; ++e) {
                int b = (int)(unsigned char)sgn[co_l * 2304 + (ci0 + e) * 9 + tp];
                int sh = (e & 3) * 8;
                if (e < 4) b0 |= b << sh; else if (e < 8) b1 |= b << sh;
                else if (e < 12) b2 |= b << sh; else b3 |= b << sh;
            }
            v4i o; o.x = b0; o.y = b1; o.z = b2; o.w = b3;
            dst[((tp * 8 + ks) * 8 + g) * 64 + lane] = o;
        }
    } else {
        // x-part: 784 blocks; thread = (ch-chunk, 4 consecutive pixels)
        const int local = bid - 32;            // 0..783
        const int ch = local / 49;             // 16 chunks
        const int i4 = (local % 49) * 256 + t; // 0..12543
        if (ch == 0 && i4 < 1024) stats[i4] = 0.0;  // zero all 4 stat arrays
        const int gp = i4 * 4;
        const int n = gp / HW, p = gp % HW;    // p..p+3 within one image (784%4==0)
        const float* base = x + (size_t)n * C * HW + (size_t)(ch * 16) * HW + p;
        int a0=0,a1=0,a2=0,a3=0;   // pixel0 words
        int b0=0,b1=0,b2=0,b3=0;   // pixel1
        int c0=0,c1=0,c2=0,c3=0;   // pixel2
        int d0=0,d1=0,d2=0,d3=0;   // pixel3
        XPE( 0,a0,b0,c0,d0, 0) XPE( 1,a0,b0,c0,d0, 8) XPE( 2,a0,b0,c0,d0,16) XPE( 3,a0,b0,c0,d0,24)
        XPE( 4,a1,b1,c1,d1, 0) XPE( 5,a1,b1,c1,d1, 8) XPE( 6,a1,b1,c1,d1,16) XPE( 7,a1,b1,c1,d1,24)
        XPE( 8,a2,b2,c2,d2, 0) XPE( 9,a2,b2,c2,d2, 8) XPE(10,a2,b2,c2,d2,16) XPE(11,a2,b2,c2,d2,24)
        XPE(12,a3,b3,c3,d3, 0) XPE(13,a3,b3,c3,d3, 8) XPE(14,a3,b3,c3,d3,16) XPE(15,a3,b3,c3,d3,24)
        v4i* dst = xb + (size_t)ch * GP + gp;
        v4i o0; o0.x=a0; o0.y=a1; o0.z=a2; o0.w=a3; dst[0] = o0;
        v4i o1; o1.x=b0; o1.y=b1; o1.z=b2; o1.w=b3; dst[1] = o1;
        v4i o2; o2.x=c0; o2.y=c1; o2.z=c2; o2.w=c3; dst[2] = o2;
        v4i o3; o3.x=d0; o3.y=d1; o3.z=d2; o3.w=d3; dst[3] = o3;
    }
}

// ---------------------------------------------------------------------------
// inline finalize (per block; ~1 fp64 op/thread — measured-cheap, R15 lesson)
// ---------------------------------------------------------------------------
__device__ __forceinline__ void finalize_coefs(int t, const double* __restrict__ sum,
                                               const double* __restrict__ sumsq,
                                               const float* __restrict__ gamma,
                                               const float* __restrict__ beta,
                                               float* __restrict__ s_scale,
                                               float* __restrict__ s_shift) {
    double mean = sum[t] / (double)CNT;
    double var  = sumsq[t] / (double)CNT - mean * mean;
    double inv  = 1.0 / sqrt(var + 1e-5);
    s_scale[t] = (float)inv * gamma[t];
    s_shift[t] = beta[t] - (float)(mean * inv) * gamma[t];
}

// ---------------------------------------------------------------------------
// BN1 + binarize -> i8 plane-major (finalize inline; 4 pixels/thread).
// sign(clip(z)) == sign(z); binarize(0)=+1.
// ---------------------------------------------------------------------------
typedef short short4v __attribute__((ext_vector_type(4)));

#define SPE(e, pw0, pw1, pw2, pw3, sh) { \
    const short4v v = *(const short4v*)(base + (size_t)(e) * HW); \
    const float sc = s_scale[chb + (e)], sf = s_shift[chb + (e)]; \
    pw0 |= SB((float)v.x * sc + sf) << (sh); pw1 |= SB((float)v.y * sc + sf) << (sh); \
    pw2 |= SB((float)v.z * sc + sf) << (sh); pw3 |= SB((float)v.w * sc + sf) << (sh); }

__global__ void bn_signpack_kernel(const short* __restrict__ y,
                                   const double* __restrict__ sum,
                                   const double* __restrict__ sumsq,
                                   const float* __restrict__ gamma,
                                   const float* __restrict__ beta,
                                   v4i* __restrict__ xb) {
    __shared__ float s_scale[C], s_shift[C];
    const int t = threadIdx.x;
    finalize_coefs(t, sum, sumsq, gamma, beta, s_scale, s_shift);
    __syncthreads();
    const int local = blockIdx.x;          // 784 blocks
    const int ch = local / 49;
    const int i4 = (local % 49) * 256 + t;
    const int gp = i4 * 4;
    const int n = gp / HW, p = gp % HW;
    const short* base = y + (size_t)n * C * HW + (size_t)(ch * 16) * HW + p;
    const int chb = ch * 16;
    int a0=0,a1=0,a2=0,a3=0;
    int b0=0,b1=0,b2=0,b3=0;
    int c0=0,c1=0,c2=0,c3=0;
    int d0=0,d1=0,d2=0,d3=0;
    SPE( 0,a0,b0,c0,d0, 0) SPE( 1,a0,b0,c0,d0, 8) SPE( 2,a0,b0,c0,d0,16) SPE( 3,a0,b0,c0,d0,24)
    SPE( 4,a1,b1,c1,d1, 0) SPE( 5,a1,b1,c1,d1, 8) SPE( 6,a1,b1,c1,d1,16) SPE( 7,a1,b1,c1,d1,24)
    SPE( 8,a2,b2,c2,d2, 0) SPE( 9,a2,b2,c2,d2, 8) SPE(10,a2,b2,c2,d2,16) SPE(11,a2,b2,c2,d2,24)
    SPE(12,a3,b3,c3,d3, 0) SPE(13,a3,b3,c3,d3, 8) SPE(14,a3,b3,c3,d3,16) SPE(15,a3,b3,c3,d3,24)
    v4i* dst = xb + (size_t)ch * GP + gp;
    v4i o0; o0.x=a0; o0.y=a1; o0.z=a2; o0.w=a3; dst[0] = o0;
    v4i o1; o1.x=b0; o1.y=b1; o1.z=b2; o1.w=b3; dst[1] = o1;
    v4i o2; o2.x=c0; o2.y=c1; o2.z=c2; o2.w=c3; dst[2] = o2;
    v4i o3; o3.x=d0; o3.y=d1; o3.z=d2; o3.w=d3; dst[3] = o3;
}

// ---------------------------------------------------------------------------
// bconv on mfma_i32_32x32x32_i8. Block = 128 px x 256 co; 4 waves; wave wn
// owns co [wn*64, wn*64+64) as 2 groups of 32. Ping-pong double-buffer,
// zero-row border select, 4-consecutive-pixel stores.
// ---------------------------------------------------------------------------

#define Z16 {0,0,0,0,0,0,0,0,0,0,0,0,0,0,0,0}
#define ACC_DECL v16i c00=Z16,c10=Z16,c20=Z16,c30=Z16, \
                      c01=Z16,c11=Z16,c21=Z16,c31=Z16;

#define MFMA32(a,b,c) c = __builtin_amdgcn_mfma_i32_32x32x32_i8(a, b, c, 0, 0, 0);

// load this wave's 2 B-frags for one (tp,ks): kidx = (tp*8+ks)*512
#define B_LOAD2(P, kidx) { const v4i* bp = wbf + (kidx) + bwl; \
    P##0 = bp[0]; P##1 = bp[64]; }

// read 4 A-frags (one ks: m=0..3); R* = row*16 (or ZROW), S* = swizzle
#define A_READ4(P, cb) { \
    P##0 = xl[R0 + ((cb) ^ S0)]; P##1 = xl[R1 + ((cb) ^ S1)]; \
    P##2 = xl[R2 + ((cb) ^ S2)]; P##3 = xl[R3 + ((cb) ^ S3)]; }

// 8 MFMAs: c{m}{gl} += A{m} * B{gl}, setprio-wrapped
#define MFMA_C8(A,B) __builtin_amdgcn_s_setprio(1); \
    MFMA32(A##0,B##0,c00) MFMA32(A##1,B##0,c10) MFMA32(A##2,B##0,c20) MFMA32(A##3,B##0,c30) \
    MFMA32(A##0,B##1,c01) MFMA32(A##1,B##1,c11) MFMA32(A##2,B##1,c21) MFMA32(A##3,B##1,c31) \
    __builtin_amdgcn_s_setprio(0);

#define TV1(m) { const bool mk = ((unsigned)(cm##m + dc) < 28u) && \
                                 ((unsigned)(rm##m + dr) < 28u); \
    const int r = 32 + l31 + 32 * (m) + doff; \
    R##m = mk ? r * 16 : ZROW; S##m = mk ? (r & 15) : 0; }
#define TAPVARS(TPX) { const int dr = (TPX)/3 - 1, dc = (TPX)%3 - 1; \
    const int doff = dr * W + dc; \
    TV1(0) TV1(1) TV1(2) TV1(3) }

#define PMV(m) { const int gx = gp0 + (m)*32 + l31; \
    const int pm = gx % HW; rm##m = pm / W; cm##m = pm % W; }

// epilogue: quad q of acc (m,gl): 4 consecutive pixels, one channel
#define EPIQ(m,gl,q) { \
    const int gpv = gp0 + (m)*32 + (q)*8 + lh4; \
    const int nn = gpv / HW; const int pp = gpv - nn*HW; \
    const size_t base = (size_t)nn*(C*HW) + (size_t)(cob + (gl)*32) * HW + pp; \
    if constexpr (HAS_RES) { \
        const float4 r4 = *(const float4*)(residual + base); \
        float4 o; \
        o.x = (float)(c##m##gl[(q)*4+0]) + r4.x; \
        o.y = (float)(c##m##gl[(q)*4+1]) + r4.y; \
        o.z = (float)(c##m##gl[(q)*4+2]) + r4.z; \
        o.w = (float)(c##m##gl[(q)*4+3]) + r4.w; \
        *(float4*)((float*)yout + base) = o; \
        sy##gl += o.x + o.y + o.z + o.w; \
        sq##gl += o.x*o.x + o.y*o.y + o.z*o.z + o.w*o.w; \
    } else { \
        const int i0 = c##m##gl[(q)*4+0], i1 = c##m##gl[(q)*4+1]; \
        const int i2 = c##m##gl[(q)*4+2], i3 = c##m##gl[(q)*4+3]; \
        int2 o; o.x = (i0 & 0xFFFF) | (i1 << 16); o.y = (i2 & 0xFFFF) | (i3 << 16); \
        *(int2*)((short*)yout + base) = o; \
        const float f0 = (float)i0, f1 = (float)i1, f2 = (float)i2, f3 = (float)i3; \
        sy##gl += f0 + f1 + f2 + f3; \
        sq##gl += f0*f0 + f1*f1 + f2*f2 + f3*f3; \
    } }
#define EPIM(m) EPIQ(m,0,0) EPIQ(m,0,1) EPIQ(m,0,2) EPIQ(m,0,3) \
                EPIQ(m,1,0) EPIQ(m,1,1) EPIQ(m,1,2) EPIQ(m,1,3)

#define RED32(gl) { float s1 = sy##gl, s2 = sq##gl; \
    s1 += __shfl_down(s1, 32); s2 += __shfl_down(s2, 32); \
    if (l < 32) { const int co = wn*64 + (gl)*32 + l; \
        atomicAdd(&sum[co], (double)s1); atomicAdd(&sumsq[co], (double)s2); } }

template<bool HAS_RES, typename OUT_T>
__launch_bounds__(256, 2)
__global__ void bconv_mfma(const v4i* __restrict__ xb,
                           const v4i* __restrict__ wbf,
                           const float* __restrict__ residual,
                           OUT_T* __restrict__ yout,
                           double* __restrict__ sum, double* __restrict__ sumsq) {
    __shared__ v4i xl[LROWS * 16 + 16];     // 192 data rows + zero row (49.4 KB)
    const int t   = threadIdx.x;
    const int gp0 = blockIdx.x * MT;

    // stage 192 rows x 16 chunks, coalesced reads, swizzled LDS writes
    for (int pass = 0; pass < 12; ++pass) {
        const int i = pass * 256 + t;
        const int c = i / LROWS;            // plane 0..15
        const int r = i - c * LROWS;        // local row 0..191
        int gsrc = min(max(gp0 - 32 + r, 0), GP - 1);
        xl[r * 16 + (c ^ (r & 15))] = xb[(size_t)c * GP + gsrc];
    }
    if (t < 16) { v4i z = {0,0,0,0}; xl[ZROW + t] = z; }   // zero row
    __syncthreads();

    const int l = t & 63, wn = t >> 6;
    const int l31 = l & 31, lh = l >> 5, lh4 = lh * 4;

    int rm0, cm0, rm1, cm1, rm2, cm2, rm3, cm3;
    PMV(0) PMV(1) PMV(2) PMV(3)

    ACC_DECL
    const int bwl = wn * 128 + l;           // this wave's B lane base (g = wn*2)

    int R0,R1,R2,R3, S0,S1,S2,S3;
    TAPVARS(0)
    v4i bP0,bP1, bQ0,bQ1;
    v4i aP0,aP1,aP2,aP3, aQ0,aQ1,aQ2,aQ3;
    B_LOAD2(bP, 0)                  // (tap0, ks0)
    A_READ4(aP, lh)

#pragma unroll 1
    for (int tp = 0; tp < 9; ++tp) {
        const int tb = tp * 4096;
        B_LOAD2(bQ, tb +  512) A_READ4(aQ,  2 + lh) MFMA_C8(aP, bP)
        B_LOAD2(bP, tb + 1024) A_READ4(aP,  4 + lh) MFMA_C8(aQ, bQ)
        B_LOAD2(bQ, tb + 1536) A_READ4(aQ,  6 + lh) MFMA_C8(aP, bP)
        B_LOAD2(bP, tb + 2048) A_READ4(aP,  8 + lh) MFMA_C8(aQ, bQ)
        B_LOAD2(bQ, tb + 2560) A_READ4(aQ, 10 + lh) MFMA_C8(aP, bP)
        B_LOAD2(bP, tb + 3072) A_READ4(aP, 12 + lh) MFMA_C8(aQ, bQ)
        B_LOAD2(bQ, tb + 3584) A_READ4(aQ, 14 + lh) MFMA_C8(aP, bP)
        // ks=7: next-tap vars; prefetch (tp+1, ks0); compute (tp,7)
        const int tpn = (tp < 8) ? tp + 1 : 8;
        TAPVARS(tpn)
        B_LOAD2(bP, tpn * 4096)
        A_READ4(aP, lh)
        MFMA_C8(aQ, bQ)
    }

    // ---- epilogue: 4-consecutive-pixel stores + per-channel stats ----
    float sy0 = 0, sy1 = 0, sq0 = 0, sq1 = 0;
    const int cob = wn * 64 + l31;
    EPIM(0) EPIM(1) EPIM(2) EPIM(3)
    RED32(0) RED32(1)
}

// ---------------------------------------------------------------------------
// Final: finalize inline + out = clip(z*s+b, -1, 1), float4
// ---------------------------------------------------------------------------
__global__ void bn_clip_kernel(const float4* __restrict__ z,
                               const double* __restrict__ sum,
                               const double* __restrict__ sumsq,
                               const float* __restrict__ gamma,
                               const float* __restrict__ beta,
                               float4* __restrict__ out) {
    __shared__ float s_scale[C], s_shift[C];
    const int t = threadIdx.x;
    finalize_coefs(t, sum, sumsq, gamma, beta, s_scale, s_shift);
    __syncthreads();
    for (int i = blockIdx.x * blockDim.x + t; i < TOTAL / 4;
         i += gridDim.x * blockDim.x) {
        int c = (i / (HW / 4)) & (C - 1);
        float s = s_scale[c], b = s_shift[c];
        float4 v = z[i];
        v.x = fminf(1.f, fmaxf(-1.f, v.x * s + b));
        v.y = fminf(1.f, fmaxf(-1.f, v.y * s + b));
        v.z = fminf(1.f, fmaxf(-1.f, v.z * s + b));
        v.w = fminf(1.f, fmaxf(-1.f, v.w * s + b));
        out[i] = v;
    }
}

// ---------------------------------------------------------------------------
extern "C" void kernel_launch(void* const* d_in, const int* in_sizes, int n_in,
                              void* d_out, int out_size, void* d_ws, size_t ws_size,
                              hipStream_t stream) {
    const float* x  = (const float*)d_in[0];
    const float* w1 = (const float*)d_in[1];
    const float* w2 = (const float*)d_in[2];
    const float* g1 = (const float*)d_in[3];
    const float* b1 = (const float*)d_in[4];
    const float* g2 = (const float*)d_in[5];
    const float* b2 = (const float*)d_in[6];
    float* out = (float*)d_out;

    char* ws = (char*)d_ws;
    size_t off = 0;
    float* z2 = (float*)(ws + off);   off += (size_t)TOTAL * 4;        // 51.4 MB
    v4i* xb1  = (v4i*)(ws + off);     off += (size_t)GP * 16 * 16;     // 12.85 MB
    v4i* xb2  = (v4i*)(ws + off);     off += (size_t)GP * 16 * 16;     // 12.85 MB
    v4i* wbf1 = (v4i*)(ws + off);     off += (size_t)36864 * 16;       // 590 KB
    v4i* wbf2 = (v4i*)(ws + off);     off += (size_t)36864 * 16;
    double* stats = (double*)(ws + off); off += 4 * 256 * 8;
    double* sum1 = stats, *sumsq1 = stats + 256, *sum2 = stats + 512, *sumsq2 = stats + 768;

    // y1 (i16) lives in d_out as scratch; fully rewritten by bn_clip at the end
    short* y1 = (short*)d_out;

    // pre-pass: weight packs (32-wide frag order) + x pack (4px/thread) + stats zero
    pack_all_kernel<<<32 + 784, 256, 0, stream>>>(w1, w2, x, wbf1, wbf2, xb1, stats);

    // conv1: y1 (i16) -> d_out scratch, fused BN1 stats
    bconv_mfma<false, short><<<NBLK, 256, 0, stream>>>(xb1, wbf1, nullptr, y1, sum1, sumsq1);
    // finalize1 (inline) + BN1 + hardtanh + binarize -> i8 planes
    bn_signpack_kernel<<<784, 256, 0, stream>>>(y1, sum1, sumsq1, g1, b1, xb2);
    // conv2 + residual, fused BN2 stats, z2 -> ws
    bconv_mfma<true, float><<<NBLK, 256, 0, stream>>>(xb2, wbf2, x, z2, sum2, sumsq2);
    // finalize2 (inline) + BN2 + hardtanh -> out
    bn_clip_kernel<<<4096, 256, 0, stream>>>((const float4*)z2, sum2, sumsq2, g2, b2,
                                             (float4*)out);
}

// Round 12
// 207.775 us; speedup vs baseline: 1.0652x; 1.0652x over previous
//
#include <hip/hip_runtime.h>
#include <stdint.h>

typedef int v4i __attribute__((ext_vector_type(4)));
typedef short short4v __attribute__((ext_vector_type(4)));

// Problem constants
constexpr int C     = 256;           // channels (in == out)
constexpr int H     = 28, W = 28;
constexpr int HW    = H * W;         // 784
constexpr int NB    = 64;            // batch
constexpr int GP    = NB * HW;       // 50176 flattened pixels
constexpr int CNT   = GP;            // per-channel reduction count
constexpr int TOTAL = NB * C * HW;   // 12,845,056
constexpr int MT    = 112;           // pixels per block
constexpr int NBLK  = GP / MT;       // 448 conv tiles, exact
constexpr int LROWS = 176;           // staged rows: gp0-32 .. gp0+143
constexpr int ZROW  = LROWS * 16;    // zero-row base (v4i index)
constexpr int GPB   = GP / 256;      // 196 pixel-blocks per channel-chunk

// ---------------------------------------------------------------------------
// R17 = Round-8 champion (203us) reverted EXACTLY, plus ONE delta:
// conv2 stores raw conv as i16 (25.7MB) instead of conv+residual f32
// (51.4MB); residual add moves to bn_clip (bit-exact: conv fits i16,
// (float)conv + x identical in either place). Stats in conv2 unchanged
// (conv+res, it already reads x). bn_clip's new x-read should be
// L3-resident (~130MB working set < 256MB L3).
// R16 post-mortem: 32x32x32 slower (53.5 vs 46.9) despite halved bank
// conflicts -> LDS-pipe theory refuted; 16x16x64/MT=112 is the empirical
// conv optimum. Conv is banked; no further conv changes.
// Frag order (A and B identical) for mfma_i32_16x16x64_i8: lane l holds
// ch = g*16 + (l&15), k = (l>>4)*16+e. wbf[((tp*4+kb)*16+g)*64+l].
// +1 -> 0x01, -1 -> 0xFF, zero-pad = 0x00.
// ---------------------------------------------------------------------------

#define SB(f) ((f) < 0.f ? 0xFF : 0x01)

__device__ __forceinline__ void pack_x_item(int local, int t, const float* __restrict__ x,
                                            v4i* __restrict__ xb, double* __restrict__ stats) {
    const int ch = local / GPB;
    const int gp = (local % GPB) * 256 + t;
    if (ch == 0 && gp < 1024) stats[gp] = 0.0;   // zero sum1/sumsq1/sum2/sumsq2
    const int n = gp / HW, p = gp % HW;
    const float* base = x + (size_t)n * C * HW + p + (size_t)(ch * 16) * HW;
    int b0 = 0, b1 = 0, b2 = 0, b3 = 0;
#pragma unroll
    for (int e = 0; e < 16; ++e) {
        float v = base[(size_t)e * HW];
        int b = SB(v);
        int sh = (e & 3) * 8;
        if (e < 4) b0 |= b << sh; else if (e < 8) b1 |= b << sh;
        else if (e < 12) b2 |= b << sh; else b3 |= b << sh;
    }
    v4i o; o.x = b0; o.y = b1; o.z = b2; o.w = b3;
    xb[(size_t)ch * GP + gp] = o;
}

__device__ __forceinline__ void finalize_coefs(int t, const double* __restrict__ sum,
                                               const double* __restrict__ sumsq,
                                               const float* __restrict__ gamma,
                                               const float* __restrict__ beta,
                                               float* __restrict__ s_scale,
                                               float* __restrict__ s_shift) {
    double mean = sum[t] / (double)CNT;
    double var  = sumsq[t] / (double)CNT - mean * mean;
    double inv  = 1.0 / sqrt(var + 1e-5);
    s_scale[t] = (float)inv * gamma[t];
    s_shift[t] = beta[t] - (float)(mean * inv) * gamma[t];
}

// ---------------------------------------------------------------------------
// pack_all: w-part as LDS transpose (32 blocks) + x-part (3136 blocks).
// ---------------------------------------------------------------------------
__global__ void pack_all_kernel(const float* __restrict__ pw1, const float* __restrict__ pw2,
                                const float* __restrict__ x,
                                v4i* __restrict__ wbf1, v4i* __restrict__ wbf2,
                                v4i* __restrict__ xb, double* __restrict__ stats) {
    __shared__ signed char sgn[36864];     // 16 co x 2304 (ci,tap) sign bytes
    const int t = threadIdx.x;
    const int bid = blockIdx.x;
    if (bid < 32) {                        // w-part: (tensor, g) LDS transpose
        const int g = bid & 15;
        const float* w = (bid >> 4) ? pw2 : pw1;
        v4i* dst       = (bid >> 4) ? wbf2 : wbf1;
        const float4* wg = (const float4*)(w + (size_t)g * 16 * 2304);
        int* sg4 = (int*)sgn;
        for (int pass = 0; pass < 36; ++pass) {        // 9216 float4 / 256
            const int m4 = pass * 256 + t;
            float4 v = wg[m4];
            int pk = SB(v.x) | (SB(v.y) << 8) | (SB(v.z) << 16) | (SB(v.w) << 24);
            sg4[m4] = pk;
        }
        __syncthreads();
        const int l = t & 63, kb = t >> 6;
        const int colb = (l & 15) * 2304;              // co_local * 2304
        const int cib  = kb * 64 + (l >> 4) * 16;      // ci0
        for (int tp = 0; tp < 9; ++tp) {
            int b0 = 0, b1 = 0, b2 = 0, b3 = 0;
#pragma unroll
            for (int e = 0; e < 16; ++e) {
                int b = (int)(unsigned char)sgn[colb + (cib + e) * 9 + tp];
                int sh = (e & 3) * 8;
                if (e < 4) b0 |= b << sh; else if (e < 8) b1 |= b << sh;
                else if (e < 12) b2 |= b << sh; else b3 |= b << sh;
            }
            v4i o; o.x = b0; o.y = b1; o.z = b2; o.w = b3;
            dst[((tp * 4 + kb) * 16 + g) * 64 + l] = o;
        }
    } else {
        pack_x_item(bid - 32, t, x, xb, stats);
    }
}

// ---------------------------------------------------------------------------
// Fused finalize (per block) + BN1 + binarize -> i8 plane-major.
// ---------------------------------------------------------------------------
__global__ void bn_signpack_kernel(const short* __restrict__ y,
                                   const double* __restrict__ sum,
                                   const double* __restrict__ sumsq,
                                   const float* __restrict__ gamma,
                                   const float* __restrict__ beta,
                                   v4i* __restrict__ xb) {
    __shared__ float s_scale[C], s_shift[C];
    const int t = threadIdx.x;
    finalize_coefs(t, sum, sumsq, gamma, beta, s_scale, s_shift);
    __syncthreads();
    const int local = blockIdx.x;          // 3136 blocks
    const int ch = local / GPB;
    const int gp = (local % GPB) * 256 + t;
    const int n = gp / HW, p = gp % HW;
    const short* base = y + (size_t)n * C * HW + p + (size_t)(ch * 16) * HW;
    int b0 = 0, b1 = 0, b2 = 0, b3 = 0;
#pragma unroll
    for (int e = 0; e < 16; ++e) {
        const int c = ch * 16 + e;
        float z = (float)base[(size_t)e * HW] * s_scale[c] + s_shift[c];
        int b = SB(z);
        int sh = (e & 3) * 8;
        if (e < 4) b0 |= b << sh; else if (e < 8) b1 |= b << sh;
        else if (e < 12) b2 |= b << sh; else b3 |= b << sh;
    }
    v4i o; o.x = b0; o.y = b1; o.z = b2; o.w = b3;
    xb[(size_t)ch * GP + gp] = o;
}

// ---------------------------------------------------------------------------
// bconv: R13 structure (banked: 46 us, MfmaUtil 23.5). MT=112, ping-pong
// double-buffer, zero-row border select. R17 delta: HAS_RES path now stores
// raw conv as i16 (residual only feeds the stats).
// ---------------------------------------------------------------------------

#define ACCD(m) v4i c##m##_0={0,0,0,0}, c##m##_1={0,0,0,0}, \
                    c##m##_2={0,0,0,0}, c##m##_3={0,0,0,0};
#define ACC_DECL ACCD(0) ACCD(1) ACCD(2) ACCD(3) ACCD(4) ACCD(5) ACCD(6)

#define MFMA(a,b,c) c = __builtin_amdgcn_mfma_i32_16x16x64_i8(a, b, c, 0, 0, 0);

#define B_LOADQ(P, idx) { const v4i* bp = wbf + (idx); \
    P##0 = bp[0]; P##1 = bp[64]; P##2 = bp[128]; P##3 = bp[192]; }

#define ARD(P, m, cb) P##m = xl[R##m + ((cb) ^ S##m)];
#define ARDALL(P, cb) ARD(P,0,cb) ARD(P,1,cb) ARD(P,2,cb) ARD(P,3,cb) \
                      ARD(P,4,cb) ARD(P,5,cb) ARD(P,6,cb)

#define MFMAG(A,B,g) MFMA(A##0,B##g,c0_##g) MFMA(A##1,B##g,c1_##g) MFMA(A##2,B##g,c2_##g) \
                     MFMA(A##3,B##g,c3_##g) MFMA(A##4,B##g,c4_##g) MFMA(A##5,B##g,c5_##g) \
                     MFMA(A##6,B##g,c6_##g)
#define MFMA_C(A,B) __builtin_amdgcn_s_setprio(1); \
    MFMAG(A,B,0) MFMAG(A,B,1) MFMAG(A,B,2) MFMAG(A,B,3) \
    __builtin_amdgcn_s_setprio(0);

#define TV1(m) { const bool mk = ((unsigned)(cm##m + dc) < 28u) && \
                                 ((unsigned)(rm##m + dr) < 28u); \
    R##m = mk ? (lrb + 16 * (m)) * 16 : ZROW; S##m = mk ? sm : 0; }
#define TAPVARS(TPX) { const int dr = (TPX)/3 - 1, dc = (TPX)%3 - 1; \
    const int lrb = 32 + llo + dr * W + dc; const int sm = lrb & 15; \
    TV1(0) TV1(1) TV1(2) TV1(3) TV1(4) TV1(5) TV1(6) }

#define PMV(m) const int gx##m = gp0 + (m)*16 + llo; \
    const int pmv##m = gx##m % HW; \
    const int rm##m = pmv##m / W, cm##m = pmv##m % W;

// epilogue: one C frag (mt,g). HAS_RES: stats on conv+res, STORE raw conv i16.
#define EPIV(m,g) { \
    const int gpv = gp0 + (m)*16 + lhi*4; \
    const int nn = gpv / HW; const int pp = gpv - nn*HW; \
    const size_t base = (size_t)nn*(C*HW) + (size_t)(wn*64+(g)*16+llo)*HW + pp; \
    const v4i cc = c##m##_##g; \
    int2 o; o.x = (cc.x & 0xFFFF) | (cc.y << 16); \
    o.y = (cc.z & 0xFFFF) | (cc.w << 16); \
    *(int2*)(yout + base) = o; \
    if constexpr (HAS_RES) { \
        const float4 r4 = *(const float4*)(residual + base); \
        const float f0 = (float)cc.x + r4.x, f1 = (float)cc.y + r4.y; \
        const float f2 = (float)cc.z + r4.z, f3 = (float)cc.w + r4.w; \
        sy##g += f0 + f1 + f2 + f3; \
        sq##g += f0*f0 + f1*f1 + f2*f2 + f3*f3; \
    } else { \
        const float f0 = (float)cc.x, f1 = (float)cc.y, f2 = (float)cc.z, f3 = (float)cc.w; \
        sy##g += f0 + f1 + f2 + f3; \
        sq##g += f0*f0 + f1*f1 + f2*f2 + f3*f3; \
    } }
#define EPIM(m) EPIV(m,0) EPIV(m,1) EPIV(m,2) EPIV(m,3)

#define REDN(g) { float s1 = sy##g, s2 = sq##g; \
    s1 += __shfl_down(s1, 32); s1 += __shfl_down(s1, 16); \
    s2 += __shfl_down(s2, 32); s2 += __shfl_down(s2, 16); \
    if (l < 16) { const int co = wn*64 + (g)*16 + l; \
        atomicAdd(&sum[co], (double)s1); atomicAdd(&sumsq[co], (double)s2); } }

template<bool HAS_RES>
__launch_bounds__(256, 2)
__global__ void bconv_mfma(const v4i* __restrict__ xb,
                           const v4i* __restrict__ wbf,
                           const float* __restrict__ residual,
                           short* __restrict__ yout,
                           double* __restrict__ sum, double* __restrict__ sumsq) {
    __shared__ v4i xl[LROWS * 16 + 16];     // 176 data rows + zero row (45.3 KB)
    const int t   = threadIdx.x;
    const int gp0 = blockIdx.x * MT;

    // stage 176 rows x 16 chunks, coalesced reads, swizzled LDS writes
    for (int pass = 0; pass < 11; ++pass) {
        const int i = pass * 256 + t;
        const int c = i / LROWS;            // plane 0..15
        const int r = i - c * LROWS;        // local row 0..175
        int gsrc = min(max(gp0 - 32 + r, 0), GP - 1);
        xl[r * 16 + (c ^ (r & 15))] = xb[(size_t)c * GP + gsrc];
    }
    if (t < 16) { v4i z = {0,0,0,0}; xl[ZROW + t] = z; }   // zero row
    __syncthreads();

    const int l = t & 63, wn = t >> 6;
    const int llo = l & 15, lhi = l >> 4;

    PMV(0) PMV(1) PMV(2) PMV(3) PMV(4) PMV(5) PMV(6)

    ACC_DECL
    const int bw = wn * 256 + l;

    int R0,R1,R2,R3,R4,R5,R6, S0,S1,S2,S3,S4,S5,S6;
    TAPVARS(0)
    v4i bP0,bP1,bP2,bP3, bQ0,bQ1,bQ2,bQ3;
    v4i aP0,aP1,aP2,aP3,aP4,aP5,aP6, aQ0,aQ1,aQ2,aQ3,aQ4,aQ5,aQ6;
    B_LOADQ(bP, bw)                 // (tap0, kb0)
    ARDALL(aP, lhi)

#pragma unroll 1
    for (int tp = 0; tp < 9; ++tp) {
        const int tb = bw + tp * 4096;
        // kb0: prefetch (tp,1); compute (tp,0)
        B_LOADQ(bQ, tb + 1024)
        ARDALL(aQ, 4 + lhi)
        MFMA_C(aP, bP)
        // kb1: prefetch (tp,2); compute (tp,1)
        B_LOADQ(bP, tb + 2048)
        ARDALL(aP, 8 + lhi)
        MFMA_C(aQ, bQ)
        // kb2: prefetch (tp,3); compute (tp,2)
        B_LOADQ(bQ, tb + 3072)
        ARDALL(aQ, 12 + lhi)
        MFMA_C(aP, bP)
        // kb3: next-tap vars; prefetch (tp+1,0); compute (tp,3)
        const int tpn = (tp < 8) ? tp + 1 : 8;
        TAPVARS(tpn)
        B_LOADQ(bP, bw + tpn * 4096)
        ARDALL(aP, lhi)
        MFMA_C(aQ, bQ)
    }

    // ---- epilogue: vectorized store + per-channel stats ----
    float sy0 = 0, sy1 = 0, sy2 = 0, sy3 = 0;
    float sq0 = 0, sq1 = 0, sq2 = 0, sq3 = 0;
    EPIM(0) EPIM(1) EPIM(2) EPIM(3) EPIM(4) EPIM(5) EPIM(6)
    REDN(0) REDN(1) REDN(2) REDN(3)
}

// ---------------------------------------------------------------------------
// Final: finalize inline + out = clip(((float)y2 + x)*s + b, -1, 1).
// y2 = raw conv2 i16; residual add deferred here (bit-exact vs fused form).
// ---------------------------------------------------------------------------
__global__ void bn_clip_kernel(const short* __restrict__ y2,
                               const float* __restrict__ x,
                               const double* __restrict__ sum,
                               const double* __restrict__ sumsq,
                               const float* __restrict__ gamma,
                               const float* __restrict__ beta,
                               float4* __restrict__ out) {
    __shared__ float s_scale[C], s_shift[C];
    const int t = threadIdx.x;
    finalize_coefs(t, sum, sumsq, gamma, beta, s_scale, s_shift);
    __syncthreads();
    const float4* x4 = (const float4*)x;
    for (int i = blockIdx.x * blockDim.x + t; i < TOTAL / 4;
         i += gridDim.x * blockDim.x) {
        int c = (i / (HW / 4)) & (C - 1);
        float s = s_scale[c], b = s_shift[c];
        const short4v yv = *(const short4v*)(y2 + (size_t)i * 4);
        const float4 xv = x4[i];
        float4 v;
        v.x = fminf(1.f, fmaxf(-1.f, ((float)yv.x + xv.x) * s + b));
        v.y = fminf(1.f, fmaxf(-1.f, ((float)yv.y + xv.y) * s + b));
        v.z = fminf(1.f, fmaxf(-1.f, ((float)yv.z + xv.z) * s + b));
        v.w = fminf(1.f, fmaxf(-1.f, ((float)yv.w + xv.w) * s + b));
        out[i] = v;
    }
}

// ---------------------------------------------------------------------------
extern "C" void kernel_launch(void* const* d_in, const int* in_sizes, int n_in,
                              void* d_out, int out_size, void* d_ws, size_t ws_size,
                              hipStream_t stream) {
    const float* x  = (const float*)d_in[0];
    const float* w1 = (const float*)d_in[1];
    const float* w2 = (const float*)d_in[2];
    const float* g1 = (const float*)d_in[3];
    const float* b1 = (const float*)d_in[4];
    const float* g2 = (const float*)d_in[5];
    const float* b2 = (const float*)d_in[6];
    float* out = (float*)d_out;

    char* ws = (char*)d_ws;
    size_t off = 0;
    short* y2 = (short*)(ws + off);   off += (size_t)TOTAL * 2;        // 25.7 MB
    v4i* xb1  = (v4i*)(ws + off);     off += (size_t)GP * 16 * 16;     // 12.85 MB
    v4i* xb2  = (v4i*)(ws + off);     off += (size_t)GP * 16 * 16;     // 12.85 MB
    v4i* wbf1 = (v4i*)(ws + off);     off += (size_t)36864 * 16;       // 590 KB
    v4i* wbf2 = (v4i*)(ws + off);     off += (size_t)36864 * 16;
    double* stats = (double*)(ws + off); off += 4 * 256 * 8;
    double* sum1 = stats, *sumsq1 = stats + 256, *sum2 = stats + 512, *sumsq2 = stats + 768;

    // y1 (i16) lives in d_out as scratch; fully rewritten by bn_clip at the end
    short* y1 = (short*)d_out;

    // pre-pass: weight packs (LDS-transpose) + x pack + stats zero
    pack_all_kernel<<<32 + 16 * GPB, 256, 0, stream>>>(w1, w2, x, wbf1, wbf2, xb1, stats);

    // conv1: y1 (i16) -> d_out scratch, fused BN1 stats
    bconv_mfma<false><<<NBLK, 256, 0, stream>>>(xb1, wbf1, nullptr, y1, sum1, sumsq1);
    // finalize1 (inline) + BN1 + hardtanh + binarize -> i8 planes
    bn_signpack_kernel<<<16 * GPB, 256, 0, stream>>>(y1, sum1, sumsq1, g1, b1, xb2);
    // conv2: raw conv -> y2 (i16), stats on conv+residual
    bconv_mfma<true><<<NBLK, 256, 0, stream>>>(xb2, wbf2, x, y2, sum2, sumsq2);
    // finalize2 (inline) + residual add + BN2 + hardtanh -> out
    bn_clip_kernel<<<4096, 256, 0, stream>>>(y2, x, sum2, sumsq2, g2, b2, (float4*)out);
}